// Round 6
// baseline (348.992 us; speedup 1.0000x reference)
//
#include <hip/hip_runtime.h>

#define T_TOK 1024
#define H_DIM 1024
#define I_DIM 4096
#define NE 8
#define BK 64

typedef __attribute__((ext_vector_type(8))) short bf16x8;
typedef __attribute__((ext_vector_type(4))) float f32x4;

__device__ __forceinline__ unsigned short f2bf(float x) {
  union { float f; unsigned u; } v; v.f = x;
  unsigned r = v.u + 0x7fffu + ((v.u >> 16) & 1u);  // RNE
  return (unsigned short)(r >> 16);
}

__device__ __forceinline__ unsigned cvt_pk_bf16(float a, float b) {
  unsigned r;
  asm("v_cvt_pk_bf16_f32 %0, %1, %2" : "=v"(r) : "v"(a), "v"(b));
  return r;
}

// async global->LDS DMA, 16B per lane (guide: the only staging that scales in-flight bytes)
__device__ __forceinline__ void dma16(const void* g, void* l) {
  __builtin_amdgcn_global_load_lds(
      (const __attribute__((address_space(1))) unsigned*)g,
      (__attribute__((address_space(3))) unsigned*)l, 16, 0, 0);
}

#define WAITVM(N) asm volatile("s_waitcnt vmcnt(" #N ")" ::: "memory")
#define WAITLGKM() asm volatile("s_waitcnt lgkmcnt(0)" ::: "memory")

// ---------------- routing: softmax top-2 + renormalize ----------------
__global__ void k_route(const float* __restrict__ gates, int* __restrict__ counts,
                        int* __restrict__ tok_idx, float* __restrict__ tok_w,
                        int* __restrict__ tok_cpy) {
  int t = blockIdx.x * blockDim.x + threadIdx.x;
  if (t >= T_TOK) return;
  float g[NE];
#pragma unroll
  for (int e = 0; e < NE; ++e) g[e] = gates[t * NE + e];
  int i1 = 0; float g1 = g[0];
#pragma unroll
  for (int e = 1; e < NE; ++e) if (g[e] > g1) { g1 = g[e]; i1 = e; }
  int i2 = -1; float g2 = -1e30f;
#pragma unroll
  for (int e = 0; e < NE; ++e) if (e != i1 && g[e] > g2) { g2 = g[e]; i2 = e; }
  float wa = 1.0f / (1.0f + expf(g2 - g1));
  float wb = 1.0f - wa;
  int s1 = atomicAdd(&counts[i1], 1);
  tok_idx[i1 * T_TOK + s1] = t; tok_w[i1 * T_TOK + s1] = wa; tok_cpy[i1 * T_TOK + s1] = 0;
  int s2 = atomicAdd(&counts[i2], 1);
  tok_idx[i2 * T_TOK + s2] = t; tok_w[i2 * T_TOK + s2] = wb; tok_cpy[i2 * T_TOK + s2] = 1;
}

// ---------------- pack token copies -> compact bf16 rows ----------------
__global__ void k_pack(const float* __restrict__ hs, const int* __restrict__ counts,
                       const int* __restrict__ tok_idx, const float* __restrict__ tok_w,
                       const int* __restrict__ tok_cpy, unsigned short* __restrict__ xpack,
                       float* __restrict__ row_w, int* __restrict__ inv_row) {
  int e = blockIdx.x >> 10, slot = blockIdx.x & 1023;
  if (slot >= counts[e]) return;
  int off = 0;
#pragma unroll
  for (int i = 0; i < NE; ++i) if (i < e) off += counts[i];
  int row = off + slot;
  int tok = tok_idx[e * T_TOK + slot];
  if (threadIdx.x == 0) {
    row_w[row] = tok_w[e * T_TOK + slot];
    inv_row[tok * 2 + tok_cpy[e * T_TOK + slot]] = row;
  }
  float4 v = ((const float4*)(hs + (size_t)tok * H_DIM))[threadIdx.x];
  uint2 o; o.x = cvt_pk_bf16(v.x, v.y); o.y = cvt_pk_bf16(v.z, v.w);
  ((uint2*)(xpack + (size_t)row * H_DIM))[threadIdx.x] = o;
}

// ================= GEMM1: DMA-staged, 128 tok x 128 w1-rows, BK=64 =================
// XCD x = expert; per XCD: panels pe (64 act-col groups), mt adjacent for L2 w1 reuse.
// LDS: A bf16 [128][64] swz, B fp32 [128][64] swz; double buffer = 96 KB.
__global__ __launch_bounds__(256)
void k_gemm1(const float* __restrict__ w1, const unsigned short* __restrict__ xpack,
             const int* __restrict__ counts, unsigned short* __restrict__ act) {
  int b = blockIdx.x;
  int x = b & 7;            // XCD = expert
  int i = b >> 3;           // [0,512)
  int pe = i >> 3;          // panel-in-expert [0,64)
  int mt = i & 7;
  int e = x, nt = pe;
  int cnt = counts[e];
  int m0 = mt * 128;
  if (m0 >= cnt) return;
  int off = 0;
#pragma unroll
  for (int k = 0; k < NE; ++k) if (k < e) off += counts[k];
  int n0 = nt * 64;         // act column base (64 cols per panel)

  __shared__ __align__(16) unsigned char AsB[2][16384];
  __shared__ __align__(16) unsigned char BsB[2][32768];

  int tid = threadIdx.x;
  int lane = tid & 63, wid = tid >> 6;
  int wm = wid & 1, wn = wid >> 1;
  int lr = lane & 15, lg = lane >> 4;

  const float* w1e = w1 + (size_t)e * (2 * I_DIM) * H_DIM;
  const unsigned short* xb = xpack + (size_t)(off + m0) * H_DIM;

  // staging constants (source pre-swizzled so linear LDS + swizzled read match)
  int arow = tid >> 3, acc8 = tid & 7;
  const unsigned short* aS0 = xb + (size_t)arow * H_DIM + (size_t)((acc8 ^ (arow & 7)) * 8);
  int brow = tid >> 4, bcc = tid & 15;
  int bccs = bcc ^ (brow & 7);

  f32x4 acc[4][4];
#pragma unroll
  for (int p = 0; p < 4; ++p)
#pragma unroll
    for (int q = 0; q < 4; ++q) acc[p][q] = (f32x4){0.f, 0.f, 0.f, 0.f};

#define G1_STAGE(BUF, T)                                                        \
  {                                                                             \
    int k0 = (T) * BK;                                                          \
    unsigned char* aD = &AsB[BUF][tid * 16];                                    \
    _Pragma("unroll") for (int c = 0; c < 4; ++c)                               \
        dma16(aS0 + (size_t)c * 32 * H_DIM + k0, aD + c * 4096);                \
    unsigned char* bD = &BsB[BUF][tid * 16];                                    \
    _Pragma("unroll") for (int c = 0; c < 8; ++c) {                             \
      int grow = ((c & 1) ? I_DIM : 0) + n0 + ((c >> 1) << 4) + brow;           \
      dma16(w1e + (size_t)grow * H_DIM + bccs * 4 + k0, bD + c * 4096);         \
    }                                                                           \
  }

#define G1_COMPUTE(BUF)                                                         \
  _Pragma("unroll") for (int kk = 0; kk < 2; ++kk) {                            \
    bf16x8 a[4];                                                                \
    _Pragma("unroll") for (int mr = 0; mr < 4; ++mr) {                          \
      int r = wm * 64 + mr * 16 + lr;                                           \
      int ca = kk * 4 + lg;                                                     \
      a[mr] = *(const bf16x8*)&AsB[BUF][r * 128 + ((ca ^ (r & 7)) << 4)];       \
    }                                                                           \
    _Pragma("unroll") for (int nr = 0; nr < 4; ++nr) {                          \
      int r = wn * 64 + nr * 16 + lr;                                           \
      int c0 = kk * 8 + lg * 2;                                                 \
      f32x4 lo = *(const f32x4*)&BsB[BUF][r * 256 + ((c0 ^ (r & 7)) << 4)];     \
      f32x4 hi = *(const f32x4*)&BsB[BUF][r * 256 + (((c0 + 1) ^ (r & 7)) << 4)]; \
      union { unsigned u[4]; bf16x8 v; } bb;                                    \
      bb.u[0] = cvt_pk_bf16(lo[0], lo[1]); bb.u[1] = cvt_pk_bf16(lo[2], lo[3]); \
      bb.u[2] = cvt_pk_bf16(hi[0], hi[1]); bb.u[3] = cvt_pk_bf16(hi[2], hi[3]); \
      _Pragma("unroll") for (int mr = 0; mr < 4; ++mr)                          \
          acc[mr][nr] = __builtin_amdgcn_mfma_f32_16x16x32_bf16(                \
              a[mr], bb.v, acc[mr][nr], 0, 0, 0);                               \
    }                                                                           \
  }

  G1_STAGE(0, 0);
  G1_STAGE(1, 1);
  for (int t = 0; t < 16; ++t) {
    if (t == 15) { WAITVM(0); } else { WAITVM(12); }   // counted: stage(t) done, stage(t+1) in flight
    __builtin_amdgcn_s_barrier();
    __builtin_amdgcn_sched_barrier(0);
    if (t & 1) { G1_COMPUTE(1); } else { G1_COMPUTE(0); }
    WAITLGKM();
    __builtin_amdgcn_s_barrier();
    if (t + 2 < 16) { if (t & 1) G1_STAGE(1, t + 2) else G1_STAGE(0, t + 2) }
  }
#undef G1_STAGE
#undef G1_COMPUTE

  // SwiGLU epilogue: frag nr parity = gate/up; col = n0 + (wn*2 + nr/2)*16 + lr
#pragma unroll
  for (int mr = 0; mr < 4; ++mr) {
#pragma unroll
    for (int pp = 0; pp < 2; ++pp) {
      f32x4 g = acc[mr][2 * pp], u = acc[mr][2 * pp + 1];
      int ncol = n0 + (wn * 2 + pp) * 16 + lr;
#pragma unroll
      for (int q = 0; q < 4; ++q) {
        int rl = wm * 64 + mr * 16 + lg * 4 + q;
        if (m0 + rl < cnt) {
          float gv = g[q];
          float av = gv / (1.0f + expf(-gv)) * u[q];
          act[(size_t)(off + m0 + rl) * I_DIM + ncol] = f2bf(av);
        }
      }
    }
  }
}

// ================= GEMM2: DMA-staged, 128 tok x 128 h-cols, split-K x4 =================
__global__ __launch_bounds__(256)
void k_gemm2(const float* __restrict__ w2, const unsigned short* __restrict__ act,
             const int* __restrict__ counts, const float* __restrict__ row_w,
             float* __restrict__ yp) {
  int b = blockIdx.x;
  int x = b & 7;            // XCD = expert
  int i = b >> 3;           // [0,256)
  int pc = i >> 3;          // [0,32): nt*4 + kc
  int mt = i & 7;
  int e = x, nt = pc >> 2, kc = pc & 3;
  int cnt = counts[e];
  int m0 = mt * 128;
  if (m0 >= cnt) return;
  int off = 0;
#pragma unroll
  for (int k = 0; k < NE; ++k) if (k < e) off += counts[k];
  int n0 = nt * 128;
  int kbase = kc * 1024;

  __shared__ __align__(16) unsigned char AsB[2][16384];
  __shared__ __align__(16) unsigned char BsB[2][32768];

  int tid = threadIdx.x;
  int lane = tid & 63, wid = tid >> 6;
  int wm = wid & 1, wn = wid >> 1;
  int lr = lane & 15, lg = lane >> 4;

  const float* w2e = w2 + (size_t)e * H_DIM * I_DIM;
  const unsigned short* ab = act + (size_t)(off + m0) * I_DIM + kbase;

  int arow = tid >> 3, acc8 = tid & 7;
  const unsigned short* aS0 = ab + (size_t)arow * I_DIM + (size_t)((acc8 ^ (arow & 7)) * 8);
  int brow = tid >> 4, bcc = tid & 15;
  int bccs = bcc ^ (brow & 7);

  f32x4 acc[4][4];
#pragma unroll
  for (int p = 0; p < 4; ++p)
#pragma unroll
    for (int q = 0; q < 4; ++q) acc[p][q] = (f32x4){0.f, 0.f, 0.f, 0.f};

#define G2_STAGE(BUF, T)                                                        \
  {                                                                             \
    int k0 = (T) * BK;                                                          \
    unsigned char* aD = &AsB[BUF][tid * 16];                                    \
    _Pragma("unroll") for (int c = 0; c < 4; ++c)                               \
        dma16(aS0 + (size_t)c * 32 * I_DIM + k0, aD + c * 4096);                \
    unsigned char* bD = &BsB[BUF][tid * 16];                                    \
    _Pragma("unroll") for (int c = 0; c < 8; ++c) {                             \
      int grow = n0 + c * 16 + brow;                                            \
      dma16(w2e + (size_t)grow * I_DIM + kbase + bccs * 4 + k0, bD + c * 4096); \
    }                                                                           \
  }

#define G2_COMPUTE(BUF)                                                         \
  _Pragma("unroll") for (int kk = 0; kk < 2; ++kk) {                            \
    bf16x8 a[4];                                                                \
    _Pragma("unroll") for (int mr = 0; mr < 4; ++mr) {                          \
      int r = wm * 64 + mr * 16 + lr;                                           \
      int ca = kk * 4 + lg;                                                     \
      a[mr] = *(const bf16x8*)&AsB[BUF][r * 128 + ((ca ^ (r & 7)) << 4)];       \
    }                                                                           \
    _Pragma("unroll") for (int nr = 0; nr < 4; ++nr) {                          \
      int r = wn * 64 + nr * 16 + lr;                                           \
      int c0 = kk * 8 + lg * 2;                                                 \
      f32x4 lo = *(const f32x4*)&BsB[BUF][r * 256 + ((c0 ^ (r & 7)) << 4)];     \
      f32x4 hi = *(const f32x4*)&BsB[BUF][r * 256 + (((c0 + 1) ^ (r & 7)) << 4)]; \
      union { unsigned u[4]; bf16x8 v; } bb;                                    \
      bb.u[0] = cvt_pk_bf16(lo[0], lo[1]); bb.u[1] = cvt_pk_bf16(lo[2], lo[3]); \
      bb.u[2] = cvt_pk_bf16(hi[0], hi[1]); bb.u[3] = cvt_pk_bf16(hi[2], hi[3]); \
      _Pragma("unroll") for (int mr = 0; mr < 4; ++mr)                          \
          acc[mr][nr] = __builtin_amdgcn_mfma_f32_16x16x32_bf16(                \
              a[mr], bb.v, acc[mr][nr], 0, 0, 0);                               \
    }                                                                           \
  }

  G2_STAGE(0, 0);
  G2_STAGE(1, 1);
  for (int t = 0; t < 16; ++t) {
    if (t == 15) { WAITVM(0); } else { WAITVM(12); }
    __builtin_amdgcn_s_barrier();
    __builtin_amdgcn_sched_barrier(0);
    if (t & 1) { G2_COMPUTE(1); } else { G2_COMPUTE(0); }
    WAITLGKM();
    __builtin_amdgcn_s_barrier();
    if (t + 2 < 16) { if (t & 1) G2_STAGE(1, t + 2) else G2_STAGE(0, t + 2) }
  }
#undef G2_STAGE
#undef G2_COMPUTE

  float* ypc = yp + (size_t)kc * (2048 * H_DIM);
#pragma unroll
  for (int mr = 0; mr < 4; ++mr) {
#pragma unroll
    for (int q = 0; q < 4; ++q) {
      int rl = wm * 64 + mr * 16 + lg * 4 + q;
      if (m0 + rl >= cnt) continue;
      int grow = off + m0 + rl;
      float wgt = row_w[grow];
      float* yrow = ypc + (size_t)grow * H_DIM;
#pragma unroll
      for (int nr = 0; nr < 4; ++nr) {
        int ncol = n0 + wn * 64 + nr * 16 + lr;
        yrow[ncol] = acc[mr][nr][q] * wgt;
      }
    }
  }
}

// ---------------- combine: out[t] = sum over 2 copies x 4 K-chunks ----------------
__global__ void k_combine(const float* __restrict__ yp, const int* __restrict__ inv_row,
                          float* __restrict__ out) {
  int t = blockIdx.x, i = threadIdx.x;
  int r0 = inv_row[2 * t], r1 = inv_row[2 * t + 1];
  float4 s = make_float4(0.f, 0.f, 0.f, 0.f);
#pragma unroll
  for (int kc = 0; kc < 4; ++kc) {
    const float4* a = (const float4*)(yp + (size_t)kc * (2048 * H_DIM) + (size_t)r0 * H_DIM);
    const float4* b = (const float4*)(yp + (size_t)kc * (2048 * H_DIM) + (size_t)r1 * H_DIM);
    float4 va = a[i], vb = b[i];
    s.x += va.x + vb.x; s.y += va.y + vb.y; s.z += va.z + vb.z; s.w += va.w + vb.w;
  }
  ((float4*)(out + (size_t)t * H_DIM))[i] = s;
}

extern "C" void kernel_launch(void* const* d_in, const int* in_sizes, int n_in,
                              void* d_out, int out_size, void* d_ws, size_t ws_size,
                              hipStream_t stream) {
  const float* hs = (const float*)d_in[0];
  const float* w1 = (const float*)d_in[1];
  const float* w2 = (const float*)d_in[2];
  const float* gates = (const float*)d_in[3];
  float* out = (float*)d_out;

  char* ws = (char*)d_ws;
  int* counts = (int*)ws;                                // 32 B
  int* tok_idx = (int*)(ws + 4096);                      // 32 KB
  float* tok_w = (float*)(ws + 4096 + 32768);            // 32 KB
  int* tok_cpy = (int*)(ws + 4096 + 65536);              // 32 KB
  float* row_w = (float*)(ws + 4096 + 98304);            // 8 KB
  int* inv_row = (int*)(ws + 4096 + 98304 + 8192);       // 8 KB
  unsigned short* xpack = (unsigned short*)(ws + (1 << 17));   // 4 MB
  unsigned short* act = (unsigned short*)(ws + (8u << 20));    // 16 MB
  float* yp = (float*)(ws + (32u << 20));                      // 4 x 8 MB

  hipMemsetAsync(counts, 0, NE * sizeof(int), stream);
  k_route<<<dim3(4), dim3(256), 0, stream>>>(gates, counts, tok_idx, tok_w, tok_cpy);
  k_pack<<<dim3(NE * T_TOK), dim3(256), 0, stream>>>(hs, counts, tok_idx, tok_w, tok_cpy,
                                                     xpack, row_w, inv_row);
  k_gemm1<<<dim3(4096), dim3(256), 0, stream>>>(w1, xpack, counts, act);
  k_gemm2<<<dim3(2048), dim3(256), 0, stream>>>(w2, act, counts, row_w, yp);
  k_combine<<<dim3(T_TOK), dim3(256), 0, stream>>>(yp, inv_row, out);
}